// Round 1
// baseline (1352.590 us; speedup 1.0000x reference)
//
#include <hip/hip_runtime.h>
#include <math.h>

#define BB 512   // batch
#define TT 256   // time steps
#define EE 128   // hidden
#define GG 512   // 4*E gates
#define XROW 257 // T+1

__device__ __forceinline__ float sigmoidf_(float v) {
    return 1.0f / (1.0f + __expf(-v));
}
__device__ __forceinline__ float tanhf_(float v) {
    float vc = fminf(fmaxf(v, -15.0f), 15.0f);
    float e = __expf(2.0f * vc);
    return (e - 1.0f) / (e + 1.0f);
}

// ---------------------------------------------------------------------------
// Encoder: grid = B/2 blocks, 1024 threads. Block j handles batches 2j, 2j+1.
// Thread t owns gate row r = t>>1, column half (t&1): 64 weights in VGPRs.
// ---------------------------------------------------------------------------
__global__ __launch_bounds__(1024) void enc_kernel(
    const float* __restrict__ x,     // (B, 257)
    const float* __restrict__ wih,   // (512)
    const float* __restrict__ whh,   // (512,128)
    const float* __restrict__ bias,  // (512)
    float* __restrict__ hc_ws)       // h:(B,E) then c:(B,E)
{
    const int t = threadIdx.x;
    const int r = t >> 1;
    const int half = t & 1;
    const int b0 = blockIdx.x * 2;

    __shared__ __align__(16) float h_lds[2][EE];
    __shared__ float gates[2][GG];
    __shared__ float x_lds[2];

    // weights: whh[r*128 + half*64 + k] == whh[t*64 + k]
    float w[64];
    {
        const float4* wp = (const float4*)(whh + t * 64);
        #pragma unroll
        for (int k = 0; k < 16; ++k) ((float4*)w)[k] = wp[k];
    }
    const float wih_r = wih[r];
    const float b_r = bias[r];

    if (t < 2 * EE) h_lds[t >> 7][t & 127] = 0.0f;
    float c_reg = 0.0f;
    if (t < 2) x_lds[t] = x[(b0 + t) * XROW + 0];
    __syncthreads();

    for (int step = 0; step < TT; ++step) {
        // ---- dot phase: gates = h @ W^T (+ x*wih + b) ----
        float acc0 = 0.0f, acc1 = 0.0f;
        const float4* h0 = (const float4*)(&h_lds[0][half * 64]);
        const float4* h1 = (const float4*)(&h_lds[1][half * 64]);
        #pragma unroll
        for (int k = 0; k < 16; ++k) {
            float4 a = h0[k];
            float4 b4 = h1[k];
            acc0 = fmaf(w[4*k+0], a.x, acc0);
            acc0 = fmaf(w[4*k+1], a.y, acc0);
            acc0 = fmaf(w[4*k+2], a.z, acc0);
            acc0 = fmaf(w[4*k+3], a.w, acc0);
            acc1 = fmaf(w[4*k+0], b4.x, acc1);
            acc1 = fmaf(w[4*k+1], b4.y, acc1);
            acc1 = fmaf(w[4*k+2], b4.z, acc1);
            acc1 = fmaf(w[4*k+3], b4.w, acc1);
        }
        acc0 += __shfl_xor(acc0, 1);
        acc1 += __shfl_xor(acc1, 1);
        // half==0 writes batch0 gate, half==1 writes batch1 gate
        float accsel = (half == 0) ? acc0 : acc1;
        gates[half][r] = accsel + x_lds[half] * wih_r + b_r;
        __syncthreads();

        // ---- update phase: 256 threads, (b,e) = (t>>7, t&127) ----
        if (t < 256) {
            int bb = t >> 7, e = t & 127;
            float gi = gates[bb][e];
            float gf = gates[bb][EE + e];
            float gg = gates[bb][2 * EE + e];
            float go = gates[bb][3 * EE + e];
            float i_ = sigmoidf_(gi);
            float f_ = sigmoidf_(gf);
            float g_ = tanhf_(gg);
            float o_ = sigmoidf_(go);
            float c_new = f_ * c_reg + i_ * g_;
            c_reg = c_new;
            h_lds[bb][e] = o_ * tanhf_(c_new);
        }
        if (t >= 256 && t < 258 && step + 1 < TT) {
            x_lds[t - 256] = x[(b0 + (t - 256)) * XROW + (step + 1)];
        }
        __syncthreads();
    }

    if (t < 256) {
        int bb = t >> 7, e = t & 127;
        hc_ws[(b0 + bb) * EE + e] = h_lds[bb][e];
        hc_ws[BB * EE + (b0 + bb) * EE + e] = c_reg;
    }
}

// ---------------------------------------------------------------------------
// Decoder: grid = B blocks, 1024 threads. Block b handles batch b, id-gathered
// weights register-resident (same mapping as encoder).
// ---------------------------------------------------------------------------
__global__ __launch_bounds__(1024) void dec_kernel(
    const float* __restrict__ x,      // (B, 257)
    const float* __restrict__ dwih,   // (16, 512)
    const float* __restrict__ dwhh,   // (16, 512, 128)
    const float* __restrict__ db,     // (16, 512)
    const float* __restrict__ lw,     // (16, 128)
    const float* __restrict__ lb,     // (16)
    const float* __restrict__ hc_ws,
    float* __restrict__ out)          // (B, T)
{
    const int t = threadIdx.x;
    const int r = t >> 1;
    const int half = t & 1;
    const int b = blockIdx.x;

    __shared__ __align__(16) float h_lds[EE];
    __shared__ float gates[GG];
    __shared__ float u_lds;
    __shared__ float osum[2];

    const int id = (int)x[b * XROW + TT];

    float w[64];
    {
        const float4* wp = (const float4*)(dwhh + id * GG * EE + t * 64);
        #pragma unroll
        for (int k = 0; k < 16; ++k) ((float4*)w)[k] = wp[k];
    }
    const float wih_r = dwih[id * GG + r];
    const float b_r = db[id * GG + r];
    const float lb_v = lb[id];

    float c_reg = 0.0f;
    float wl_e = 0.0f;
    if (t < EE) {  // full waves 0,1
        float hv = hc_ws[b * EE + t];
        h_lds[t] = hv;
        c_reg = hc_ws[BB * EE + b * EE + t];
        wl_e = lw[id * EE + t];
        float p = hv * wl_e;
        #pragma unroll
        for (int off = 32; off >= 1; off >>= 1) p += __shfl_xor(p, off);
        if ((t & 63) == 0) osum[t >> 6] = p;
    }
    __syncthreads();
    if (t == 0) u_lds = osum[0] + osum[1] + lb_v;  // u0
    __syncthreads();

    for (int step = 0; step < TT; ++step) {
        // previous step's output store (osum stable during dot phase)
        if (t == 0 && step > 0) {
            out[b * TT + (TT - step)] = osum[0] + osum[1] + lb_v;
        }
        // ---- dot phase ----
        float acc = 0.0f;
        const float4* h0 = (const float4*)(&h_lds[half * 64]);
        float u = u_lds;
        #pragma unroll
        for (int k = 0; k < 16; ++k) {
            float4 a = h0[k];
            acc = fmaf(w[4*k+0], a.x, acc);
            acc = fmaf(w[4*k+1], a.y, acc);
            acc = fmaf(w[4*k+2], a.z, acc);
            acc = fmaf(w[4*k+3], a.w, acc);
        }
        acc += __shfl_xor(acc, 1);
        if (half == 0) gates[r] = acc + u * wih_r + b_r;
        __syncthreads();

        // ---- update phase: threads 0..127 ----
        if (t < EE) {
            int e = t;
            float gi = gates[e];
            float gf = gates[EE + e];
            float gg = gates[2 * EE + e];
            float go = gates[3 * EE + e];
            float i_ = sigmoidf_(gi);
            float f_ = sigmoidf_(gf);
            float g_ = tanhf_(gg);
            float o_ = sigmoidf_(go);
            float c_new = f_ * c_reg + i_ * g_;
            c_reg = c_new;
            float h_new = o_ * tanhf_(c_new);
            h_lds[e] = h_new;
            float p = h_new * wl_e;
            #pragma unroll
            for (int off = 32; off >= 1; off >>= 1) p += __shfl_xor(p, off);
            if ((t & 63) == 0) osum[t >> 6] = p;
        }
        // prefetch next input scalar: rev sequence
        if (t == 256 && step + 1 < TT) {
            u_lds = x[b * XROW + (255 - step)];
        }
        __syncthreads();
    }
    if (t == 0) out[b * TT + 0] = osum[0] + osum[1] + lb_v;
}

extern "C" void kernel_launch(void* const* d_in, const int* in_sizes, int n_in,
                              void* d_out, int out_size, void* d_ws, size_t ws_size,
                              hipStream_t stream) {
    const float* x       = (const float*)d_in[0];
    const float* enc_wih = (const float*)d_in[1];
    const float* enc_whh = (const float*)d_in[2];
    const float* enc_b   = (const float*)d_in[3];
    const float* dec_wih = (const float*)d_in[4];
    const float* dec_whh = (const float*)d_in[5];
    const float* dec_b   = (const float*)d_in[6];
    const float* lin_w   = (const float*)d_in[7];
    const float* lin_b   = (const float*)d_in[8];
    float* out = (float*)d_out;
    float* ws  = (float*)d_ws;  // needs 2*B*E floats = 512 KB

    hipLaunchKernelGGL(enc_kernel, dim3(BB / 2), dim3(1024), 0, stream,
                       x, enc_wih, enc_whh, enc_b, ws);
    hipLaunchKernelGGL(dec_kernel, dim3(BB), dim3(1024), 0, stream,
                       x, dec_wih, dec_whh, dec_b, lin_w, lin_b, ws, out);
}

// Round 2
// 1103.005 us; speedup vs baseline: 1.2263x; 1.2263x over previous
//
#include <hip/hip_runtime.h>
#include <math.h>

#define BB 512   // batch
#define TT 256   // time steps
#define EE 128   // hidden
#define GG 512   // 4*E gates
#define XROW 257 // T+1
#define HP 136   // padded h row: halves at float offsets 0 and 68 (bank-disjoint)

__device__ __forceinline__ float sigmoidf_(float v) {
    return 1.0f / (1.0f + __expf(-v));
}
__device__ __forceinline__ float tanhf_(float v) {
    float vc = fminf(fmaxf(v, -15.0f), 15.0f);
    float e = __expf(2.0f * vc);
    return (e - 1.0f) / (e + 1.0f);
}

// 16 named float4 weight registers -- never an indexable array, so they can
// never be demoted to scratch. __launch_bounds__(1024,4) caps VGPR at 128.
#define DECL_W float4 w0,w1,w2,w3,w4,w5,w6,w7,w8,w9,w10,w11,w12,w13,w14,w15
#define LOAD_W(base) do { const float4* _wp = (const float4*)(base); \
  w0=_wp[0];  w1=_wp[1];  w2=_wp[2];  w3=_wp[3]; \
  w4=_wp[4];  w5=_wp[5];  w6=_wp[6];  w7=_wp[7]; \
  w8=_wp[8];  w9=_wp[9];  w10=_wp[10]; w11=_wp[11]; \
  w12=_wp[12]; w13=_wp[13]; w14=_wp[14]; w15=_wp[15]; } while(0)
#define FMA4(W,X,A) do{ A=fmaf((W).x,(X).x,A); A=fmaf((W).y,(X).y,A); \
                        A=fmaf((W).z,(X).z,A); A=fmaf((W).w,(X).w,A);}while(0)
// 4 rotating accumulators: dependent-FMA chain 16 deep instead of 64.
#define DOT16(HB, A0,A1,A2,A3) do { const float4* _h=(const float4*)(HB); float4 _x; \
  _x=_h[0];  FMA4(w0,_x,A0);  _x=_h[1];  FMA4(w1,_x,A1); \
  _x=_h[2];  FMA4(w2,_x,A2);  _x=_h[3];  FMA4(w3,_x,A3); \
  _x=_h[4];  FMA4(w4,_x,A0);  _x=_h[5];  FMA4(w5,_x,A1); \
  _x=_h[6];  FMA4(w6,_x,A2);  _x=_h[7];  FMA4(w7,_x,A3); \
  _x=_h[8];  FMA4(w8,_x,A0);  _x=_h[9];  FMA4(w9,_x,A1); \
  _x=_h[10]; FMA4(w10,_x,A2); _x=_h[11]; FMA4(w11,_x,A3); \
  _x=_h[12]; FMA4(w12,_x,A0); _x=_h[13]; FMA4(w13,_x,A1); \
  _x=_h[14]; FMA4(w14,_x,A2); _x=_h[15]; FMA4(w15,_x,A3); } while(0)

// ---------------------------------------------------------------------------
// Encoder: grid = B/2 blocks, 1024 threads. Block j handles batches 2j, 2j+1.
// Thread t owns gate row r = t>>1, column half (t&1): 64 weights in VGPRs.
// ---------------------------------------------------------------------------
__global__ __launch_bounds__(1024, 4) void enc_kernel(
    const float* __restrict__ x,     // (B, 257)
    const float* __restrict__ wih,   // (512)
    const float* __restrict__ whh,   // (512,128)
    const float* __restrict__ bias,  // (512)
    float* __restrict__ hc_ws)       // h:(B,E) then c:(B,E)
{
    const int t = threadIdx.x;
    const int r = t >> 1;
    const int half = t & 1;
    const int b0 = blockIdx.x * 2;

    __shared__ __align__(16) float h_lds[2][HP];
    __shared__ float gates[2][GG];
    __shared__ float x_lds[2];

    DECL_W;
    LOAD_W(whh + t * 64);  // whh[r*128 + half*64 + k] == whh[t*64 + k]
    const float wih_r = wih[r];
    const float b_r = bias[r];

    if (t < 2 * HP) ((float*)h_lds)[t] = 0.0f;
    float c_reg = 0.0f;
    if (t < 2) x_lds[t] = x[(b0 + t) * XROW + 0];
    __syncthreads();

    for (int step = 0; step < TT; ++step) {
        // ---- dot phase: gates = h @ W^T (+ x*wih + b) ----
        float a0=0.f,a1=0.f,a2=0.f,a3=0.f;
        float e0=0.f,e1=0.f,e2=0.f,e3=0.f;
        DOT16(&h_lds[0][half * 68], a0,a1,a2,a3);
        DOT16(&h_lds[1][half * 68], e0,e1,e2,e3);
        float acc0 = (a0+a1)+(a2+a3);
        float acc1 = (e0+e1)+(e2+e3);
        acc0 += __shfl_xor(acc0, 1);
        acc1 += __shfl_xor(acc1, 1);
        float accsel = (half == 0) ? acc0 : acc1;
        gates[half][r] = accsel + x_lds[half] * wih_r + b_r;
        __syncthreads();

        // ---- update phase: 256 threads, (b,e) = (t>>7, t&127) ----
        if (t < 256) {
            int bb = t >> 7, e = t & 127;
            float gi = gates[bb][e];
            float gf = gates[bb][EE + e];
            float gg = gates[bb][2 * EE + e];
            float go = gates[bb][3 * EE + e];
            float i_ = sigmoidf_(gi);
            float f_ = sigmoidf_(gf);
            float g_ = tanhf_(gg);
            float o_ = sigmoidf_(go);
            float c_new = f_ * c_reg + i_ * g_;
            c_reg = c_new;
            h_lds[bb][e + ((e >= 64) ? 4 : 0)] = o_ * tanhf_(c_new);
        }
        if (t >= 256 && t < 258 && step + 1 < TT) {
            x_lds[t - 256] = x[(b0 + (t - 256)) * XROW + (step + 1)];
        }
        __syncthreads();
    }

    if (t < 256) {
        int bb = t >> 7, e = t & 127;
        hc_ws[(b0 + bb) * EE + e] = h_lds[bb][e + ((e >= 64) ? 4 : 0)];
        hc_ws[BB * EE + (b0 + bb) * EE + e] = c_reg;
    }
}

// ---------------------------------------------------------------------------
// Decoder: grid = B blocks, 1024 threads. Block b handles batch b, id-gathered
// weights register-resident (same mapping as encoder).
// ---------------------------------------------------------------------------
__global__ __launch_bounds__(1024, 4) void dec_kernel(
    const float* __restrict__ x,      // (B, 257)
    const float* __restrict__ dwih,   // (16, 512)
    const float* __restrict__ dwhh,   // (16, 512, 128)
    const float* __restrict__ db,     // (16, 512)
    const float* __restrict__ lw,     // (16, 128)
    const float* __restrict__ lb,     // (16)
    const float* __restrict__ hc_ws,
    float* __restrict__ out)          // (B, T)
{
    const int t = threadIdx.x;
    const int r = t >> 1;
    const int half = t & 1;
    const int b = blockIdx.x;

    __shared__ __align__(16) float h_lds[HP];
    __shared__ float gates[GG];
    __shared__ float u_lds;
    __shared__ float osum[2];

    const int id = (int)x[b * XROW + TT];

    DECL_W;
    LOAD_W(dwhh + id * GG * EE + t * 64);
    const float wih_r = dwih[id * GG + r];
    const float b_r = db[id * GG + r];
    const float lb_v = lb[id];

    float c_reg = 0.0f;
    float wl_e = 0.0f;
    if (t < EE) {  // full waves 0,1
        float hv = hc_ws[b * EE + t];
        h_lds[t + ((t >= 64) ? 4 : 0)] = hv;
        c_reg = hc_ws[BB * EE + b * EE + t];
        wl_e = lw[id * EE + t];
        float p = hv * wl_e;
        #pragma unroll
        for (int off = 32; off >= 1; off >>= 1) p += __shfl_xor(p, off);
        if ((t & 63) == 0) osum[t >> 6] = p;
    }
    __syncthreads();
    if (t == 0) u_lds = osum[0] + osum[1] + lb_v;  // u0
    __syncthreads();

    for (int step = 0; step < TT; ++step) {
        // previous step's output store (osum stable during dot phase)
        if (t == 0 && step > 0) {
            out[b * TT + (TT - step)] = osum[0] + osum[1] + lb_v;
        }
        // ---- dot phase ----
        float a0=0.f,a1=0.f,a2=0.f,a3=0.f;
        float u = u_lds;
        DOT16(&h_lds[half * 68], a0,a1,a2,a3);
        float acc = (a0+a1)+(a2+a3);
        acc += __shfl_xor(acc, 1);
        if (half == 0) gates[r] = acc + u * wih_r + b_r;
        __syncthreads();

        // ---- update phase: threads 0..127 ----
        if (t < EE) {
            int e = t;
            float gi = gates[e];
            float gf = gates[EE + e];
            float gg = gates[2 * EE + e];
            float go = gates[3 * EE + e];
            float i_ = sigmoidf_(gi);
            float f_ = sigmoidf_(gf);
            float g_ = tanhf_(gg);
            float o_ = sigmoidf_(go);
            float c_new = f_ * c_reg + i_ * g_;
            c_reg = c_new;
            float h_new = o_ * tanhf_(c_new);
            h_lds[e + ((e >= 64) ? 4 : 0)] = h_new;
            float p = h_new * wl_e;
            #pragma unroll
            for (int off = 32; off >= 1; off >>= 1) p += __shfl_xor(p, off);
            if ((t & 63) == 0) osum[t >> 6] = p;
        }
        // prefetch next input scalar: rev sequence
        if (t == 256 && step + 1 < TT) {
            u_lds = x[b * XROW + (255 - step)];
        }
        __syncthreads();
    }
    if (t == 0) out[b * TT + 0] = osum[0] + osum[1] + lb_v;
}

extern "C" void kernel_launch(void* const* d_in, const int* in_sizes, int n_in,
                              void* d_out, int out_size, void* d_ws, size_t ws_size,
                              hipStream_t stream) {
    const float* x       = (const float*)d_in[0];
    const float* enc_wih = (const float*)d_in[1];
    const float* enc_whh = (const float*)d_in[2];
    const float* enc_b   = (const float*)d_in[3];
    const float* dec_wih = (const float*)d_in[4];
    const float* dec_whh = (const float*)d_in[5];
    const float* dec_b   = (const float*)d_in[6];
    const float* lin_w   = (const float*)d_in[7];
    const float* lin_b   = (const float*)d_in[8];
    float* out = (float*)d_out;
    float* ws  = (float*)d_ws;  // needs 2*B*E floats = 512 KB

    hipLaunchKernelGGL(enc_kernel, dim3(BB / 2), dim3(1024), 0, stream,
                       x, enc_wih, enc_whh, enc_b, ws);
    hipLaunchKernelGGL(dec_kernel, dim3(BB), dim3(1024), 0, stream,
                       x, dec_wih, dec_whh, dec_b, lin_w, lin_b, ws, out);
}

// Round 3
// 911.370 us; speedup vs baseline: 1.4841x; 1.2103x over previous
//
#include <hip/hip_runtime.h>
#include <math.h>

#define BB 512   // batch
#define TT 256   // time steps
#define EE 128   // hidden
#define GG 512   // 4*E gates
#define XROW 257 // T+1

__device__ __forceinline__ float sigmoidf_(float v) {
    return 1.0f / (1.0f + __expf(-v));
}
__device__ __forceinline__ float tanhf_(float v) {
    float vc = fminf(fmaxf(v, -15.0f), 15.0f);
    float e = __expf(2.0f * vc);
    return (e - 1.0f) / (e + 1.0f);
}

// Thread (rg = t&127, cg = t>>7) owns rows 4rg..4rg+3 x cols 16cg..16cg+15:
// 64 weight floats in 16 NAMED float4 regs. waves_per_eu(4,4) pins the
// register budget at 128 so they stay resident.
#define DECLW float4 w00,w01,w02,w03,w10,w11,w12,w13,w20,w21,w22,w23,w30,w31,w32,w33
#define LOADW(P) do { const float* _p = (P); \
  w00=*(const float4*)(_p);          w01=*(const float4*)(_p+4); \
  w02=*(const float4*)(_p+8);        w03=*(const float4*)(_p+12); \
  w10=*(const float4*)(_p+EE);       w11=*(const float4*)(_p+EE+4); \
  w12=*(const float4*)(_p+EE+8);     w13=*(const float4*)(_p+EE+12); \
  w20=*(const float4*)(_p+2*EE);     w21=*(const float4*)(_p+2*EE+4); \
  w22=*(const float4*)(_p+2*EE+8);   w23=*(const float4*)(_p+2*EE+12); \
  w30=*(const float4*)(_p+3*EE);     w31=*(const float4*)(_p+3*EE+4); \
  w32=*(const float4*)(_p+3*EE+8);   w33=*(const float4*)(_p+3*EE+12); } while(0)
#define FMA4(W,X,A) do{ A=fmaf((W).x,(X).x,A); A=fmaf((W).y,(X).y,A); \
                        A=fmaf((W).z,(X).z,A); A=fmaf((W).w,(X).w,A);}while(0)

// dot phase: 4 broadcast ds_read_b128 (h slice reused across 4 rows) + 64 FMA
#define DOT_PHASE() do { \
  const float4* _hp = (const float4*)(h_lds + 16*cg); \
  float4 x0=_hp[0], x1=_hp[1], x2=_hp[2], x3=_hp[3]; \
  a0=0.f; a1=0.f; a2=0.f; a3=0.f; \
  FMA4(w00,x0,a0); FMA4(w01,x1,a0); FMA4(w02,x2,a0); FMA4(w03,x3,a0); \
  FMA4(w10,x0,a1); FMA4(w11,x1,a1); FMA4(w12,x2,a1); FMA4(w13,x3,a1); \
  FMA4(w20,x0,a2); FMA4(w21,x1,a2); FMA4(w22,x2,a2); FMA4(w23,x3,a2); \
  FMA4(w30,x0,a3); FMA4(w31,x1,a3); FMA4(w32,x2,a3); FMA4(w33,x3,a3); \
  *(float4*)&part[cg*GG + rg*4] = make_float4(a0,a1,a2,a3); \
} while(0)

__global__ __launch_bounds__(1024) __attribute__((amdgpu_waves_per_eu(4, 4)))
void fused_kernel(const float* __restrict__ x,
                  const float* __restrict__ enc_wih,
                  const float* __restrict__ enc_whh,
                  const float* __restrict__ enc_bias,
                  const float* __restrict__ dec_wih,
                  const float* __restrict__ dec_whh,
                  const float* __restrict__ dec_bias,
                  const float* __restrict__ lin_w,
                  const float* __restrict__ lin_b,
                  float* __restrict__ out)
{
    const int t  = threadIdx.x;
    const int rg = t & 127;
    const int cg = t >> 7;
    const int b  = blockIdx.x;

    __shared__ __align__(16) float h_lds[EE];
    __shared__ __align__(16) float part[8 * GG];   // [cg][row] partials, 16 KB
    __shared__ float nlg[GG];                      // per-gate nonlinearity out
    __shared__ float xbuf[2];                      // double-buffered scalar input
    __shared__ float osum[2];                      // per-wave output partial sums
    __shared__ __align__(16) float out_lds[TT];

    const int id = (int)x[b * XROW + TT];

    DECLW;
    float a0, a1, a2, a3;
    float c_reg = 0.0f;

    // ---------------- encoder ----------------
    LOADW(enc_whh + (4 * rg) * EE + 16 * cg);
    float cwih = 0.f, cb = 0.f;
    if (t < GG) { cwih = enc_wih[t]; cb = enc_bias[t]; }

    if (t < EE) h_lds[t] = 0.0f;
    if (t == 512) xbuf[0] = x[b * XROW + 0];
    __syncthreads();

    for (int s = 0; s < TT; ++s) {
        DOT_PHASE();
        __syncthreads();
        // psum + nonlinearity over 512 threads (gate g = t)
        if (t < GG) {
            float sum = part[t] + part[GG + t] + part[2*GG + t] + part[3*GG + t]
                      + part[4*GG + t] + part[5*GG + t] + part[6*GG + t] + part[7*GG + t];
            float gate = sum + xbuf[s & 1] * cwih + cb;
            nlg[t] = (t >= 2*EE && t < 3*EE) ? tanhf_(gate) : sigmoidf_(gate);
        }
        if (t == 512 && s + 1 < TT) xbuf[(s + 1) & 1] = x[b * XROW + s + 1];
        __syncthreads();
        // update phase: 128 threads
        if (t < EE) {
            float i_ = nlg[t], f_ = nlg[EE + t], g_ = nlg[2*EE + t], o_ = nlg[3*EE + t];
            c_reg = f_ * c_reg + i_ * g_;
            h_lds[t] = o_ * tanhf_(c_reg);
        }
        __syncthreads();
    }

    // ---------------- u0 = h_enc . lin_w + lin_b ----------------
    const float lb_v = lin_b[id];
    float wl = 0.f;
    if (t < EE) wl = lin_w[id * EE + t];
    if (t < EE) {
        float p = h_lds[t] * wl;
        #pragma unroll
        for (int off = 32; off >= 1; off >>= 1) p += __shfl_xor(p, off);
        if ((t & 63) == 0) osum[t >> 6] = p;
    }
    __syncthreads();
    if (t == 512) xbuf[0] = osum[0] + osum[1] + lb_v;   // u0
    __syncthreads();

    // ---------------- decoder ----------------
    LOADW(dec_whh + id * GG * EE + (4 * rg) * EE + 16 * cg);
    if (t < GG) { cwih = dec_wih[id * GG + t]; cb = dec_bias[id * GG + t]; }

    for (int s = 0; s < TT; ++s) {
        DOT_PHASE();
        __syncthreads();
        if (t < GG) {
            float sum = part[t] + part[GG + t] + part[2*GG + t] + part[3*GG + t]
                      + part[4*GG + t] + part[5*GG + t] + part[6*GG + t] + part[7*GG + t];
            float gate = sum + xbuf[s & 1] * cwih + cb;
            nlg[t] = (t >= 2*EE && t < 3*EE) ? tanhf_(gate) : sigmoidf_(gate);
        }
        // u_{s+1} = rev[s] = x[b][255-s]
        if (t == 512 && s + 1 < TT) xbuf[(s + 1) & 1] = x[b * XROW + (TT - 1 - s)];
        // previous step's output (osum from step s-1, stable this phase)
        if (t == 513 && s > 0) out_lds[TT - s] = osum[0] + osum[1] + lb_v;
        __syncthreads();
        if (t < EE) {
            float i_ = nlg[t], f_ = nlg[EE + t], g_ = nlg[2*EE + t], o_ = nlg[3*EE + t];
            c_reg = f_ * c_reg + i_ * g_;
            float h_new = o_ * tanhf_(c_reg);
            h_lds[t] = h_new;
            float p = h_new * wl;
            #pragma unroll
            for (int off = 32; off >= 1; off >>= 1) p += __shfl_xor(p, off);
            if ((t & 63) == 0) osum[t >> 6] = p;
        }
        __syncthreads();
    }
    if (t == 512) out_lds[0] = osum[0] + osum[1] + lb_v;  // step 255 -> pos 0
    __syncthreads();

    if (t < 64) *(float4*)(out + b * TT + 4 * t) = ((const float4*)out_lds)[t];
}

extern "C" void kernel_launch(void* const* d_in, const int* in_sizes, int n_in,
                              void* d_out, int out_size, void* d_ws, size_t ws_size,
                              hipStream_t stream) {
    const float* x       = (const float*)d_in[0];
    const float* enc_wih = (const float*)d_in[1];
    const float* enc_whh = (const float*)d_in[2];
    const float* enc_b   = (const float*)d_in[3];
    const float* dec_wih = (const float*)d_in[4];
    const float* dec_whh = (const float*)d_in[5];
    const float* dec_b   = (const float*)d_in[6];
    const float* lin_w   = (const float*)d_in[7];
    const float* lin_b   = (const float*)d_in[8];
    float* out = (float*)d_out;

    hipLaunchKernelGGL(fused_kernel, dim3(BB), dim3(1024), 0, stream,
                       x, enc_wih, enc_whh, enc_b,
                       dec_wih, dec_whh, dec_b, lin_w, lin_b, out);
}